// Round 6
// baseline (244.306 us; speedup 1.0000x reference)
//
#include <hip/hip_runtime.h>

// YOLO v1 loss, B=16384, S=7, C=30. 192.7 MB read -> 1 float.
// Layout: pred[((b*S+i)*S+j)*30 + c]; i -> gi (x offset), j -> gj (y offset).
//
// v5b: v0/v2/v3/v4 all drain 192.7 MB at ~2.6 TB/s delivered regardless of
// access pattern / MLP / atomics; every CU pipe <20% busy; avg wave lifetime
// ~22 us vs ~1 us of work -> uncore-limited (L2-miss/IF$ service path), not
// CU-limited. Streaming kernels that DON'T allocate in IF$ hit 4.9-6.3 TB/s
// on this chip. Fix attempt: NONTEMPORAL loads (global_load ... nt) to bypass
// cache allocation for this stream-once input. v5 failed to compile:
// __builtin_nontemporal_load rejects HIP_vector_type; use a native clang
// ext_vector_type(2) instead (identical 8 B layout).
// Verification signal: FETCH_SIZE must rise ~94 MB -> ~190 MB (no L3 hits).

#define NS 7
#define NC 30
#define BLOCK 256

typedef float nfloat2 __attribute__((ext_vector_type(2)));

__global__ void zero_out_kernel(float* out) { out[0] = 0.0f; }

__global__ __launch_bounds__(BLOCK) void yolo_loss_kernel(
    const float* __restrict__ pred,
    const float* __restrict__ targ,
    float* __restrict__ partial,
    float* __restrict__ out,
    int n_cells, int atomic_mode, float inv_B)
{
    const float STEP = 1.0f / 7.0f;
    const float L_COORD = 5.0f;
    const float L_NOOBJ = 0.5f;

    int cell = blockIdx.x * blockDim.x + threadIdx.x;
    float lsum = 0.0f;
    if (cell < n_cells) {
        int j = cell % NS;            // second spatial axis -> gj
        int i = (cell / NS) % NS;     // first spatial axis  -> gi
        float gi = (float)i;
        float gj = (float)j;

        // 30 floats = 15 aligned 8-B vectors per cell (120 B stride).
        // Nontemporal: stream-once data, do not allocate in L2/IF$.
        const nfloat2* p2 = (const nfloat2*)pred + (size_t)cell * 15;
        const nfloat2* t2 = (const nfloat2*)targ + (size_t)cell * 15;
        float p[NC], t[NC];
        #pragma unroll
        for (int k = 0; k < 15; ++k) {
            nfloat2 v = __builtin_nontemporal_load(&p2[k]);
            p[2 * k] = v.x; p[2 * k + 1] = v.y;
        }
        #pragma unroll
        for (int k = 0; k < 15; ++k) {
            nfloat2 u = __builtin_nontemporal_load(&t2[k]);
            t[2 * k] = u.x; t[2 * k + 1] = u.y;
        }

        // _convert_box for target, pred box1 (ch 0:4), pred box2 (ch 5:9)
        float ta, tb, tc, td;
        {
            float cx = (t[0] + gi) * STEP;
            float cy = (t[1] + gj) * STEP;
            ta = fmaxf(cx - t[2] * 0.5f, 0.0f);
            tb = fmaxf(cy - t[3] * 0.5f, 0.0f);
            tc = fminf(cx + t[2] * 0.5f, 1.0f);
            td = fminf(cy + t[3] * 0.5f, 1.0f);
        }
        float q1, w1, e1, r1;
        {
            float cx = (p[0] + gi) * STEP;
            float cy = (p[1] + gj) * STEP;
            q1 = fmaxf(cx - p[2] * 0.5f, 0.0f);
            w1 = fmaxf(cy - p[3] * 0.5f, 0.0f);
            e1 = fminf(cx + p[2] * 0.5f, 1.0f);
            r1 = fminf(cy + p[3] * 0.5f, 1.0f);
        }
        float q2, w2, e2, r2;
        {
            float cx = (p[5] + gi) * STEP;
            float cy = (p[6] + gj) * STEP;
            q2 = fmaxf(cx - p[7] * 0.5f, 0.0f);
            w2 = fmaxf(cy - p[8] * 0.5f, 0.0f);
            e2 = fminf(cx + p[7] * 0.5f, 1.0f);
            r2 = fminf(cy + p[8] * 0.5f, 1.0f);
        }

        float tarea = (td - tb) * (tc - ta);
        // _iou(tbox, pbox): inter NOT clamped; iou = inter>0 ? inter/(union+1e-5) : 0
        float iou1, iou2;
        {
            float minx = fmaxf(ta, q1), miny = fmaxf(tb, w1);
            float maxx = fminf(tc, e1), maxy = fminf(td, r1);
            float inter = (maxy - miny) * (maxx - minx);
            float uni = (e1 - q1) * (r1 - w1) + tarea - inter;
            iou1 = (inter > 0.0f) ? inter / (uni + 1e-5f) : 0.0f;
        }
        {
            float minx = fmaxf(ta, q2), miny = fmaxf(tb, w2);
            float maxx = fminf(tc, e2), maxy = fminf(td, r2);
            float inter = (maxy - miny) * (maxx - minx);
            float uni = (e2 - q2) * (r2 - w2) + tarea - inter;
            iou2 = (inter > 0.0f) ? inter / (uni + 1e-5f) : 0.0f;
        }

        bool sel2 = (iou1 <= iou2);
        float conf_t = sel2 ? iou2 : iou1;
        float px = sel2 ? p[5] : p[0];
        float py = sel2 ? p[6] : p[1];
        float pw = sel2 ? p[7] : p[2];
        float ph = sel2 ? p[8] : p[3];
        float pconf = sel2 ? p[9] : p[4];

        float obj = (t[4] > 0.0f) ? 1.0f : 0.0f;
        float noobj = (t[4] == 0.0f) ? 1.0f : 0.0f;

        float dx = px - t[0], dy = py - t[1];
        float dw = pw - t[2], dh = ph - t[3];
        float coord = dx * dx + dy * dy + dw * dw + dh * dh;

        float dc = pconf - conf_t;
        float obj_loss = dc * dc;

        float cls = 0.0f;
        #pragma unroll
        for (int k = 10; k < NC; ++k) {
            float d = p[k] - t[k];
            cls += d * d;
        }

        float d4 = p[4] - t[4];
        float d9 = p[9] - t[9];
        float noobj_loss = d4 * d4 + d9 * d9;

        lsum = obj * (obj_loss + L_COORD * coord + cls) + L_NOOBJ * noobj * noobj_loss;
    }

    // wave(64) shuffle reduce
    #pragma unroll
    for (int off = 32; off > 0; off >>= 1)
        lsum += __shfl_down(lsum, off, 64);

    __shared__ float wsum[4];
    int lane = threadIdx.x & 63;
    int wid = threadIdx.x >> 6;
    if (lane == 0) wsum[wid] = lsum;
    __syncthreads();
    if (threadIdx.x == 0) {
        float s = (wsum[0] + wsum[1]) + (wsum[2] + wsum[3]);
        if (atomic_mode) atomicAdd(out, s * inv_B);
        else partial[blockIdx.x] = s;
    }
}

__global__ __launch_bounds__(BLOCK) void reduce_kernel(
    const float* __restrict__ partial, float* __restrict__ out,
    int n, float inv_B)
{
    const int tid = threadIdx.x;
    float s = 0.0f;
    for (int idx = tid; idx < n; idx += BLOCK) s += partial[idx];

    #pragma unroll
    for (int off = 32; off > 0; off >>= 1)
        s += __shfl_down(s, off, 64);

    __shared__ float wsum[4];
    int lane = tid & 63;
    int wid = tid >> 6;
    if (lane == 0) wsum[wid] = s;
    __syncthreads();
    if (tid == 0)
        out[0] = ((wsum[0] + wsum[1]) + (wsum[2] + wsum[3])) * inv_B;
}

extern "C" void kernel_launch(void* const* d_in, const int* in_sizes, int n_in,
                              void* d_out, int out_size, void* d_ws, size_t ws_size,
                              hipStream_t stream) {
    const float* pred = (const float*)d_in[0];
    const float* targ = (const float*)d_in[1];
    float* out = (float*)d_out;

    const int B = 16384;
    const int n_cells = B * NS * NS;  // 802816
    const float inv_B = 1.0f / (float)B;

    const int grid = (n_cells + BLOCK - 1) / BLOCK;  // 3136 exact

    if (ws_size >= (size_t)grid * sizeof(float) && d_ws != nullptr) {
        float* partial = (float*)d_ws;
        yolo_loss_kernel<<<grid, BLOCK, 0, stream>>>(pred, targ, partial, out, n_cells, 0, inv_B);
        reduce_kernel<<<1, BLOCK, 0, stream>>>(partial, out, grid, inv_B);
    } else {
        zero_out_kernel<<<1, 1, 0, stream>>>(out);
        yolo_loss_kernel<<<grid, BLOCK, 0, stream>>>(pred, targ, nullptr, out, n_cells, 1, inv_B);
    }
}

// Round 7
// 206.080 us; speedup vs baseline: 1.1855x; 1.1855x over previous
//
#include <hip/hip_runtime.h>

// YOLO v1 loss, B=16384, S=7, C=30. 192.7 MB read -> 1 float.
// Layout: pred[((b*S+i)*S+j)*30 + c]; i -> gi (x offset), j -> gj (y offset).
//
// v6: All prior variants (burst dwordx2 / LDS-staged / float4-burst / NT) show
// constant ~22 us wave lifetime regardless of occupancy and bytes -> the
// outstanding-load WINDOW per wave has always been tiny (register-allocator
// limited to ~2-4 loads in flight; v4's sched_barrier was defeated, VGPR
// stayed 68). Fix: __builtin_amdgcn_global_load_lds width=16 -> HBM->LDS with
// NO VGPR destination; all 15 chunks/thread genuinely in flight. Offered
// demand: 2 blocks/CU x 60 KB = 120 KB/CU outstanding (vs ~4-8 KB before).
// NT reverted (v5b: FETCH 94->137 MB but 72->88 us -- L3 helps, HBM-direct
// path is slower). Decision rule: <55 us => window was the cap; ~72-80 us
// despite 120 KB/CU offered => genuine uncore ceiling -> ROOFLINE.

#define NS 7
#define NC 30
#define BLOCK 256
#define CHUNKS 1920          // per array: 256 cells * 120 B / 16 B
#define TARG_OFF 7680        // float offset of targ region in sbuf
#define SB_FLOATS 15360      // 61440 B total LDS tile

typedef const __attribute__((address_space(1))) unsigned int* gas_ptr;
typedef __attribute__((address_space(3))) unsigned int* las_ptr;

__device__ __forceinline__ void async_cp16(const float* g, float* l) {
    // 16-byte direct global->LDS, no VGPR destination. LDS dest is
    // wave-uniform base + lane*16: our cid = k*256 + tid is lane-contiguous
    // per wave and each wave's 64 chunks are entirely within one array
    // (1920 % 64 == 0), so the linear layout matches HW semantics.
    __builtin_amdgcn_global_load_lds((gas_ptr)g, (las_ptr)l, 16, 0, 0);
}

__global__ void zero_out_kernel(float* out) { out[0] = 0.0f; }

__global__ __launch_bounds__(BLOCK) void yolo_loss_kernel(
    const float* __restrict__ pred,
    const float* __restrict__ targ,
    float* __restrict__ partial,
    float* __restrict__ out,
    int atomic_mode, float inv_B)
{
    const float STEP = 1.0f / 7.0f;
    const float L_COORD = 5.0f;
    const float L_NOOBJ = 0.5f;

    __shared__ float sbuf[SB_FLOATS];

    const int tid = threadIdx.x;
    const int cell = blockIdx.x * BLOCK + tid;   // 3136*256 == 802816 exact

    const float* pg = pred + (size_t)blockIdx.x * BLOCK * NC;
    const float* tg = targ + (size_t)blockIdx.x * BLOCK * NC;

    // ---- stage 61440 B tile: 3840 x 16B chunks, 15 per thread, all in flight ----
    #pragma unroll
    for (int k = 0; k < 15; ++k) {
        int cid = k * BLOCK + tid;               // 0..3839; wave-uniform branch below
        if (cid < CHUNKS) {
            async_cp16(pg + (size_t)cid * 4, sbuf + cid * 4);
        } else {
            int c2 = cid - CHUNKS;
            async_cp16(tg + (size_t)c2 * 4, sbuf + TARG_OFF + c2 * 4);
        }
    }
    asm volatile("s_waitcnt vmcnt(0)" ::: "memory");
    __syncthreads();

    // ---- per-cell loss from LDS (math identical to v0/v2: absmax 0) ----
    int j = cell % NS;            // second spatial axis -> gj
    int i = (cell / NS) % NS;     // first spatial axis  -> gi
    float gi = (float)i;
    float gj = (float)j;

    float p[NC];
    {
        const float2* s2 = (const float2*)(sbuf) + tid * (NC / 2);
        #pragma unroll
        for (int k = 0; k < NC / 2; ++k) {
            float2 v = s2[k];
            p[2 * k] = v.x; p[2 * k + 1] = v.y;
        }
    }
    const float2* s2t = (const float2*)(sbuf + TARG_OFF) + tid * (NC / 2);
    float2 t01 = s2t[0];
    float2 t23 = s2t[1];
    float2 t45 = s2t[2];
    float2 t89 = s2t[4];
    float t0 = t01.x, t1 = t01.y, t2 = t23.x, t3 = t23.y;
    float t4 = t45.x, t9 = t89.y;

    // _convert_box for target, pred box1 (ch 0:4), pred box2 (ch 5:9)
    float ta, tb, tc, td;
    {
        float cx = (t0 + gi) * STEP;
        float cy = (t1 + gj) * STEP;
        ta = fmaxf(cx - t2 * 0.5f, 0.0f);
        tb = fmaxf(cy - t3 * 0.5f, 0.0f);
        tc = fminf(cx + t2 * 0.5f, 1.0f);
        td = fminf(cy + t3 * 0.5f, 1.0f);
    }
    float q1, w1, e1, r1;
    {
        float cx = (p[0] + gi) * STEP;
        float cy = (p[1] + gj) * STEP;
        q1 = fmaxf(cx - p[2] * 0.5f, 0.0f);
        w1 = fmaxf(cy - p[3] * 0.5f, 0.0f);
        e1 = fminf(cx + p[2] * 0.5f, 1.0f);
        r1 = fminf(cy + p[3] * 0.5f, 1.0f);
    }
    float q2, w2, e2, r2;
    {
        float cx = (p[5] + gi) * STEP;
        float cy = (p[6] + gj) * STEP;
        q2 = fmaxf(cx - p[7] * 0.5f, 0.0f);
        w2 = fmaxf(cy - p[8] * 0.5f, 0.0f);
        e2 = fminf(cx + p[7] * 0.5f, 1.0f);
        r2 = fminf(cy + p[8] * 0.5f, 1.0f);
    }

    float tarea = (td - tb) * (tc - ta);
    // _iou(tbox, pbox): inter NOT clamped; iou = inter>0 ? inter/(union+1e-5) : 0
    float iou1, iou2;
    {
        float minx = fmaxf(ta, q1), miny = fmaxf(tb, w1);
        float maxx = fminf(tc, e1), maxy = fminf(td, r1);
        float inter = (maxy - miny) * (maxx - minx);
        float uni = (e1 - q1) * (r1 - w1) + tarea - inter;
        iou1 = (inter > 0.0f) ? inter / (uni + 1e-5f) : 0.0f;
    }
    {
        float minx = fmaxf(ta, q2), miny = fmaxf(tb, w2);
        float maxx = fminf(tc, e2), maxy = fminf(td, r2);
        float inter = (maxy - miny) * (maxx - minx);
        float uni = (e2 - q2) * (r2 - w2) + tarea - inter;
        iou2 = (inter > 0.0f) ? inter / (uni + 1e-5f) : 0.0f;
    }

    bool sel2 = (iou1 <= iou2);
    float conf_t = sel2 ? iou2 : iou1;
    float px = sel2 ? p[5] : p[0];
    float py = sel2 ? p[6] : p[1];
    float pw = sel2 ? p[7] : p[2];
    float ph = sel2 ? p[8] : p[3];
    float pconf = sel2 ? p[9] : p[4];

    float obj = (t4 > 0.0f) ? 1.0f : 0.0f;
    float noobj = (t4 == 0.0f) ? 1.0f : 0.0f;

    float dx = px - t0, dy = py - t1;
    float dw = pw - t2, dh = ph - t3;
    float coord = dx * dx + dy * dy + dw * dw + dh * dh;

    float dc = pconf - conf_t;
    float obj_loss = dc * dc;

    float cls = 0.0f;
    #pragma unroll
    for (int k = 0; k < 10; ++k) {
        float2 tv = s2t[5 + k];   // t[10+2k], t[11+2k]
        float d0 = p[10 + 2 * k] - tv.x;
        float d1 = p[11 + 2 * k] - tv.y;
        cls += d0 * d0;
        cls += d1 * d1;
    }

    float d4 = p[4] - t4;
    float d9 = p[9] - t9;
    float noobj_loss = d4 * d4 + d9 * d9;

    float lsum = obj * (obj_loss + L_COORD * coord + cls) + L_NOOBJ * noobj * noobj_loss;

    // wave(64) shuffle reduce
    #pragma unroll
    for (int off = 32; off > 0; off >>= 1)
        lsum += __shfl_down(lsum, off, 64);

    __shared__ float wsum[4];
    int lane = tid & 63;
    int wid = tid >> 6;
    if (lane == 0) wsum[wid] = lsum;
    __syncthreads();
    if (tid == 0) {
        float s = (wsum[0] + wsum[1]) + (wsum[2] + wsum[3]);
        if (atomic_mode) atomicAdd(out, s * inv_B);
        else partial[blockIdx.x] = s;
    }
}

__global__ __launch_bounds__(BLOCK) void reduce_kernel(
    const float* __restrict__ partial, float* __restrict__ out,
    int n, float inv_B)
{
    const int tid = threadIdx.x;
    float s = 0.0f;
    for (int idx = tid; idx < n; idx += BLOCK) s += partial[idx];

    #pragma unroll
    for (int off = 32; off > 0; off >>= 1)
        s += __shfl_down(s, off, 64);

    __shared__ float wsum[4];
    int lane = tid & 63;
    int wid = tid >> 6;
    if (lane == 0) wsum[wid] = s;
    __syncthreads();
    if (tid == 0)
        out[0] = ((wsum[0] + wsum[1]) + (wsum[2] + wsum[3])) * inv_B;
}

extern "C" void kernel_launch(void* const* d_in, const int* in_sizes, int n_in,
                              void* d_out, int out_size, void* d_ws, size_t ws_size,
                              hipStream_t stream) {
    const float* pred = (const float*)d_in[0];
    const float* targ = (const float*)d_in[1];
    float* out = (float*)d_out;

    const int B = 16384;
    const int n_cells = B * NS * NS;            // 802816
    const float inv_B = 1.0f / (float)B;
    const int grid = n_cells / BLOCK;           // 3136 exact

    if (ws_size >= (size_t)grid * sizeof(float) && d_ws != nullptr) {
        float* partial = (float*)d_ws;
        yolo_loss_kernel<<<grid, BLOCK, 0, stream>>>(pred, targ, partial, out, 0, inv_B);
        reduce_kernel<<<1, BLOCK, 0, stream>>>(partial, out, grid, inv_B);
    } else {
        zero_out_kernel<<<1, 1, 0, stream>>>(out);
        yolo_loss_kernel<<<grid, BLOCK, 0, stream>>>(pred, targ, nullptr, out, 1, inv_B);
    }
}